// Round 1
// baseline (14596.344 us; speedup 1.0000x reference)
//
#include <hip/hip_runtime.h>
#include <hip/hip_bf16.h>
#include <math.h>

#define Bc 256
#define Tc 256
#define Hc 512
#define INc 5

__device__ __forceinline__ float sigmoidf_(float x) {
    return 1.0f / (1.0f + __expf(-x));
}
__device__ __forceinline__ float tanhf_(float x) {
    float ax = fabsf(x);
    float e = __expf(2.0f * ax);
    float t = 1.0f - 2.0f / (e + 1.0f);
    return copysignf(t, x);
}

// One K=512 GEMM segment: acc[4][4] += S-tile @ W-tile^T
// Tile: 64 batches x 64 gate-cols (16 j x 4 gates). 256 threads (16x16), micro 4x4.
// LDS layout transposed [kk][col], row stride 68 words (16B aligned, ~2-way max conflicts).
__device__ __forceinline__ void gemm_seg(float acc[4][4],
                                         const float* __restrict__ S,
                                         const float* __restrict__ W,
                                         int b0i, int j0, int tid,
                                         float (*hs)[68], float (*wsm)[68])
{
    const int ty = tid >> 4, tx = tid & 15;
    const int srow = tid >> 2;        // 0..63
    const int sc4 = (tid & 3) * 4;    // kk base: 0,4,8,12
    const int gate = srow & 3, jj = srow >> 2;

    const float* sp = &S[(size_t)(b0i + srow) * Hc + sc4];
    const float* wp = &W[(size_t)(gate * Hc + j0 + jj) * Hc + sc4];

    // prefetch chunk 0
    float4 hv = *reinterpret_cast<const float4*>(sp);
    float4 wv = *reinterpret_cast<const float4*>(wp);

    for (int k0 = 0; k0 < Hc; k0 += 16) {
        hs[sc4 + 0][srow] = hv.x; hs[sc4 + 1][srow] = hv.y;
        hs[sc4 + 2][srow] = hv.z; hs[sc4 + 3][srow] = hv.w;
        wsm[sc4 + 0][srow] = wv.x; wsm[sc4 + 1][srow] = wv.y;
        wsm[sc4 + 2][srow] = wv.z; wsm[sc4 + 3][srow] = wv.w;
        __syncthreads();
        if (k0 + 16 < Hc) {  // software-prefetch next chunk (hidden under FMAs)
            hv = *reinterpret_cast<const float4*>(sp + k0 + 16);
            wv = *reinterpret_cast<const float4*>(wp + k0 + 16);
        }
#pragma unroll
        for (int kk = 0; kk < 16; kk++) {
            float4 av = *reinterpret_cast<const float4*>(&hs[kk][ty * 4]);
            float4 bv = *reinterpret_cast<const float4*>(&wsm[kk][tx * 4]);
            float a[4] = {av.x, av.y, av.z, av.w};
            float b[4] = {bv.x, bv.y, bv.z, bv.w};
#pragma unroll
            for (int i = 0; i < 4; i++)
#pragma unroll
                for (int j = 0; j < 4; j++)
                    acc[i][j] = fmaf(a[i], b[j], acc[i][j]);
        }
        __syncthreads();
    }
}

// Blocks 0..127: layer0 step t0. Blocks 128..255: layer1 step t1 (= t0-1), with
// on-the-fly input projection (K segment 2) and fused fc1 partial accumulation.
__global__ __launch_bounds__(256) void lstm_step(
    const float* __restrict__ x_time, const float* __restrict__ w_ih0,
    const float* __restrict__ w_hh0, const float* __restrict__ b0,
    const float* __restrict__ w_ih1, const float* __restrict__ w_hh1,
    const float* __restrict__ b1, const float* __restrict__ fc1_w,
    const float* __restrict__ h0r, float* __restrict__ h0w, float* __restrict__ c0,
    const float* __restrict__ h1r, float* __restrict__ h1w, float* __restrict__ c1,
    float* __restrict__ partial,
    int t0, int t1, int l0_active, int l1_active)
{
    const int layer = blockIdx.x >> 7;
    const int bid = blockIdx.x & 127;
    if (layer == 0 && !l0_active) return;
    if (layer == 1 && !l1_active) return;

    const int bb = bid & 3;          // 4 batch tiles of 64
    const int jg = bid >> 2;         // 32 j-groups of 16
    const int b0i = bb * 64;
    const int j0 = jg * 16;
    const int tid = threadIdx.x;
    const int ty = tid >> 4, tx = tid & 15;
    const int j = j0 + tx;

    __shared__ float hs[16][68];
    __shared__ float wsm[16][68];

    float acc[4][4];
#pragma unroll
    for (int i = 0; i < 4; i++)
#pragma unroll
        for (int jj2 = 0; jj2 < 4; jj2++) acc[i][jj2] = 0.f;

    if (layer == 0) {
        gemm_seg(acc, h0r, w_hh0, b0i, j0, tid, hs, wsm);

        // input projection (IN=5) + bias
        float xv[4][INc];
#pragma unroll
        for (int i = 0; i < 4; i++) {
            const float* xp = &x_time[(size_t)(b0i + ty * 4 + i) * (Tc * INc) + (size_t)t0 * INc];
#pragma unroll
            for (int d = 0; d < INc; d++) xv[i][d] = xp[d];
        }
#pragma unroll
        for (int g = 0; g < 4; g++) {
            const int grow = g * Hc + j;
            float wih[INc];
#pragma unroll
            for (int d = 0; d < INc; d++) wih[d] = w_ih0[grow * INc + d];
            const float bias = b0[grow];
#pragma unroll
            for (int i = 0; i < 4; i++) {
                float s = bias;
#pragma unroll
                for (int d = 0; d < INc; d++) s = fmaf(xv[i][d], wih[d], s);
                acc[i][g] += s;
            }
        }
#pragma unroll
        for (int i = 0; i < 4; i++) {
            const int bidx = b0i + ty * 4 + i;
            float ig = sigmoidf_(acc[i][0]);
            float fg = sigmoidf_(acc[i][1]);
            float gg = tanhf_(acc[i][2]);
            float og = sigmoidf_(acc[i][3]);
            float c = fg * c0[bidx * Hc + j] + ig * gg;
            c0[bidx * Hc + j] = c;
            h0w[bidx * Hc + j] = og * tanhf_(c);
        }
    } else {
        gemm_seg(acc, h1r, w_hh1, b0i, j0, tid, hs, wsm);   // recurrent
        gemm_seg(acc, h0r, w_ih1, b0i, j0, tid, hs, wsm);   // input proj from h0[t1]

        float hn[4];
#pragma unroll
        for (int i = 0; i < 4; i++) {
            const int bidx = b0i + ty * 4 + i;
            float ig = sigmoidf_(acc[i][0] + b1[0 * Hc + j]);
            float fg = sigmoidf_(acc[i][1] + b1[1 * Hc + j]);
            float gg = tanhf_(acc[i][2] + b1[2 * Hc + j]);
            float og = sigmoidf_(acc[i][3] + b1[3 * Hc + j]);
            float c = fg * c1[bidx * Hc + j] + ig * gg;
            c1[bidx * Hc + j] = c;
            float h = og * tanhf_(c);
            h1w[bidx * Hc + j] = h;
            hn[i] = h;
        }
        // fused fc1: partial[jg][b][n] += h * fc1_w[n, t1*H + j], reduced over the 16 j's
        const float w0 = fc1_w[(size_t)0 * (Tc * Hc) + (size_t)t1 * Hc + j];
        const float w1 = fc1_w[(size_t)1 * (Tc * Hc) + (size_t)t1 * Hc + j];
#pragma unroll
        for (int i = 0; i < 4; i++) {
            float v0 = hn[i] * w0, v1 = hn[i] * w1;
#pragma unroll
            for (int off = 1; off < 16; off <<= 1) {
                v0 += __shfl_xor(v0, off);
                v1 += __shfl_xor(v1, off);
            }
            if (tx == 0) {
                const int bidx = b0i + ty * 4 + i;
                float* p = &partial[((size_t)jg * Bc + bidx) * 2];
                p[0] += v0;
                p[1] += v1;
            }
        }
    }
}

__global__ void finalize_kernel(const float* __restrict__ x_stat,
                                const float* __restrict__ fc1_b,
                                const float* __restrict__ fc2_w, const float* __restrict__ fc2_b,
                                const float* __restrict__ fc3_w, const float* __restrict__ fc3_b,
                                const float* __restrict__ partial, float* __restrict__ out)
{
    const int b = threadIdx.x;  // 256
    float t0 = fc1_b[0], t1 = fc1_b[1];
    for (int jg = 0; jg < 32; jg++) {
        t0 += partial[((size_t)jg * Bc + b) * 2 + 0];
        t1 += partial[((size_t)jg * Bc + b) * 2 + 1];
    }
    const float s0 = fc2_b[0] + x_stat[b * 3 + 0] * fc2_w[0] + x_stat[b * 3 + 1] * fc2_w[1] + x_stat[b * 3 + 2] * fc2_w[2];
    const float s1 = fc2_b[1] + x_stat[b * 3 + 0] * fc2_w[3] + x_stat[b * 3 + 1] * fc2_w[4] + x_stat[b * 3 + 2] * fc2_w[5];
    out[b * 2 + 0] = fc3_b[0] + fc3_w[0] * s0 + fc3_w[1] * s1 + fc3_w[2] * t0 + fc3_w[3] * t1;
    out[b * 2 + 1] = fc3_b[1] + fc3_w[4] * s0 + fc3_w[5] * s1 + fc3_w[6] * t0 + fc3_w[7] * t1;
}

extern "C" void kernel_launch(void* const* d_in, const int* in_sizes, int n_in,
                              void* d_out, int out_size, void* d_ws, size_t ws_size,
                              hipStream_t stream)
{
    const float* x_time = (const float*)d_in[0];
    const float* x_stat = (const float*)d_in[1];
    const float* w_ih0 = (const float*)d_in[2];
    const float* w_hh0 = (const float*)d_in[3];
    const float* b0    = (const float*)d_in[4];
    const float* w_ih1 = (const float*)d_in[5];
    const float* w_hh1 = (const float*)d_in[6];
    const float* b1    = (const float*)d_in[7];
    const float* fc1_w = (const float*)d_in[8];
    const float* fc1_b = (const float*)d_in[9];
    const float* fc2_w = (const float*)d_in[10];
    const float* fc2_b = (const float*)d_in[11];
    const float* fc3_w = (const float*)d_in[12];
    const float* fc3_b = (const float*)d_in[13];

    float* ws = (float*)d_ws;
    float* h0 = ws;                         // 2 * B * H  (ping-pong)
    float* h1 = h0 + 2 * Bc * Hc;           // 2 * B * H  (ping-pong)
    float* c0 = h1 + 2 * Bc * Hc;           // B * H
    float* c1 = c0 + Bc * Hc;               // B * H
    float* partial = c1 + Bc * Hc;          // 32 * B * 2

    const size_t total_f = (size_t)6 * Bc * Hc + 32 * Bc * 2;
    hipMemsetAsync(d_ws, 0, total_f * sizeof(float), stream);

    for (int i = 0; i <= Tc; i++) {
        const int p = i & 1;
        const float* h0r = h0 + (size_t)p * Bc * Hc;
        float* h0wp      = h0 + (size_t)(p ^ 1) * Bc * Hc;
        const float* h1r = h1 + (size_t)(p ^ 1) * Bc * Hc;
        float* h1wp      = h1 + (size_t)p * Bc * Hc;
        lstm_step<<<256, 256, 0, stream>>>(
            x_time, w_ih0, w_hh0, b0, w_ih1, w_hh1, b1, fc1_w,
            h0r, h0wp, c0, h1r, h1wp, c1, partial,
            i, i - 1, (i < Tc) ? 1 : 0, (i >= 1) ? 1 : 0);
    }
    finalize_kernel<<<1, 256, 0, stream>>>(x_stat, fc1_b, fc2_w, fc2_b, fc3_w, fc3_b,
                                           partial, (float*)d_out);
}

// Round 2
// 5026.442 us; speedup vs baseline: 2.9039x; 2.9039x over previous
//
#include <hip/hip_runtime.h>
#include <hip/hip_bf16.h>
#include <math.h>

#define Bc 256
#define Tc 256
#define Hc 512
#define INc 5

typedef __bf16 bf16x8 __attribute__((ext_vector_type(8)));
typedef float f32x4 __attribute__((ext_vector_type(4)));

__device__ __forceinline__ float sigmoidf_(float x) {
    return 1.0f / (1.0f + __expf(-x));
}
__device__ __forceinline__ float tanhf_(float x) {
    float ax = fabsf(x);
    float e = __expf(2.0f * ax);
    float t = 1.0f - 2.0f / (e + 1.0f);
    return copysignf(t, x);
}

// acc[bi][ji] += A32xK tile @ W^T tile.  A,W row-major [*,512] bf16.
// A-frag: lane holds A[row=lane&15][k=(lane>>4)*8+j]; B-frag: W[col=lane&15][k=...].
__device__ __forceinline__ void seg(f32x4 acc[2][2],
                                    const __hip_bfloat16* __restrict__ A,
                                    const __hip_bfloat16* __restrict__ W,
                                    int b0i, int wrow0, int lane)
{
    const int lrow = lane & 15;
    const int koff = (lane >> 4) * 8;
    const bf16x8* pa0 = reinterpret_cast<const bf16x8*>(A + (size_t)(b0i + lrow) * Hc + koff);
    const bf16x8* pa1 = reinterpret_cast<const bf16x8*>(A + (size_t)(b0i + 16 + lrow) * Hc + koff);
    const bf16x8* pb0 = reinterpret_cast<const bf16x8*>(W + (size_t)(wrow0 + lrow) * Hc + koff);
    const bf16x8* pb1 = reinterpret_cast<const bf16x8*>(W + (size_t)(wrow0 + 16 + lrow) * Hc + koff);
#pragma unroll
    for (int kk = 0; kk < 16; kk++) {
        bf16x8 a0 = pa0[kk * 4];   // stride 32 bf16 per k-step
        bf16x8 a1 = pa1[kk * 4];
        bf16x8 w0 = pb0[kk * 4];
        bf16x8 w1 = pb1[kk * 4];
        acc[0][0] = __builtin_amdgcn_mfma_f32_16x16x32_bf16(a0, w0, acc[0][0], 0, 0, 0);
        acc[0][1] = __builtin_amdgcn_mfma_f32_16x16x32_bf16(a0, w1, acc[0][1], 0, 0, 0);
        acc[1][0] = __builtin_amdgcn_mfma_f32_16x16x32_bf16(a1, w0, acc[1][0], 0, 0, 0);
        acc[1][1] = __builtin_amdgcn_mfma_f32_16x16x32_bf16(a1, w1, acc[1][1], 0, 0, 0);
    }
}

// grid: 256 blocks x 256 thr. Blocks 0..127: layer0 step t0; 128..255: layer1 step t1.
// Block (bb,jb): batch [bb*32,+32), j [jb*32,+32), all 4 gates (one gate-plane per wave).
__global__ __launch_bounds__(256) void lstm_step_mfma(
    const float* __restrict__ x_time, const float* __restrict__ w_ih0,
    const float* __restrict__ b0v, const float* __restrict__ b1v,
    const float* __restrict__ fc1_w,
    const __hip_bfloat16* __restrict__ wbf_hh0,
    const __hip_bfloat16* __restrict__ wbf_ih1,
    const __hip_bfloat16* __restrict__ wbf_hh1,
    const __hip_bfloat16* __restrict__ h0r, __hip_bfloat16* __restrict__ h0w,
    float* __restrict__ c0,
    const __hip_bfloat16* __restrict__ h1r, __hip_bfloat16* __restrict__ h1w,
    float* __restrict__ c1,
    float* __restrict__ partial,
    int t0, int t1, int l0, int l1)
{
    const int layer = blockIdx.x >> 7;
    const int bid = blockIdx.x & 127;
    if (layer == 0 && !l0) return;
    if (layer == 1 && !l1) return;

    const int bb = bid >> 4, jb = bid & 15;    // XCD = jb%8 for both layers -> W L2-resident
    const int b0i = bb * 32, j0 = jb * 32;
    const int tid = threadIdx.x;
    const int lane = tid & 63;
    const int g = tid >> 6;                    // wave id = gate index

    __shared__ float gl[4][32][33];

    f32x4 acc[2][2] = {{{0.f, 0.f, 0.f, 0.f}, {0.f, 0.f, 0.f, 0.f}},
                       {{0.f, 0.f, 0.f, 0.f}, {0.f, 0.f, 0.f, 0.f}}};
    const int wrow0 = g * Hc + j0;

    if (layer == 0) {
        seg(acc, h0r, wbf_hh0, b0i, wrow0, lane);
    } else {
        seg(acc, h1r, wbf_hh1, b0i, wrow0, lane);
        seg(acc, h0r, wbf_ih1, b0i, wrow0, lane);
    }

    // D layout: row=(lane>>4)*4+reg, col=lane&15
    const int lrow = lane & 15, lgrp = lane >> 4;
#pragma unroll
    for (int bi = 0; bi < 2; bi++)
#pragma unroll
        for (int ji = 0; ji < 2; ji++)
#pragma unroll
            for (int r = 0; r < 4; r++)
                gl[g][16 * bi + lgrp * 4 + r][16 * ji + lrow] = acc[bi][ji][r];
    __syncthreads();

    // epilogue: thread -> (b = b0i + tid>>3, 4 j's at (tid&7)*4)
    const int bl = tid >> 3, j4 = tid & 7;
    const int b = b0i + bl;

    if (layer == 0) {
        float xv[INc];
#pragma unroll
        for (int d = 0; d < INc; d++)
            xv[d] = x_time[((size_t)b * Tc + t0) * INc + d];
#pragma unroll
        for (int jj = 0; jj < 4; jj++) {
            const int jl = j4 * 4 + jj, j = j0 + jl;
            float pre[4];
#pragma unroll
            for (int gg = 0; gg < 4; gg++) {
                const int row = gg * Hc + j;
                float s = gl[gg][bl][jl] + b0v[row];
#pragma unroll
                for (int d = 0; d < INc; d++)
                    s = fmaf(xv[d], w_ih0[(size_t)row * INc + d], s);
                pre[gg] = s;
            }
            float ig = sigmoidf_(pre[0]);
            float fg = sigmoidf_(pre[1]);
            float gv = tanhf_(pre[2]);
            float og = sigmoidf_(pre[3]);
            float c = fg * c0[(size_t)b * Hc + j] + ig * gv;
            c0[(size_t)b * Hc + j] = c;
            h0w[(size_t)b * Hc + j] = __float2bfloat16(og * tanhf_(c));
        }
    } else {
        float v0 = 0.f, v1 = 0.f;
#pragma unroll
        for (int jj = 0; jj < 4; jj++) {
            const int jl = j4 * 4 + jj, j = j0 + jl;
            float pre[4];
#pragma unroll
            for (int gg = 0; gg < 4; gg++)
                pre[gg] = gl[gg][bl][jl] + b1v[gg * Hc + j];
            float ig = sigmoidf_(pre[0]);
            float fg = sigmoidf_(pre[1]);
            float gv = tanhf_(pre[2]);
            float og = sigmoidf_(pre[3]);
            float c = fg * c1[(size_t)b * Hc + j] + ig * gv;
            c1[(size_t)b * Hc + j] = c;
            float h = og * tanhf_(c);
            h1w[(size_t)b * Hc + j] = __float2bfloat16(h);
            v0 = fmaf(h, fc1_w[(size_t)t1 * Hc + j], v0);
            v1 = fmaf(h, fc1_w[(size_t)Tc * Hc + (size_t)t1 * Hc + j], v1);
        }
#pragma unroll
        for (int off = 1; off < 8; off <<= 1) {
            v0 += __shfl_xor(v0, off);
            v1 += __shfl_xor(v1, off);
        }
        if (j4 == 0) {
            float* p = &partial[((size_t)jb * Bc + b) * 2];
            p[0] += v0;
            p[1] += v1;
        }
    }
}

__global__ void convert_weights(const float* __restrict__ w_hh0,
                                const float* __restrict__ w_ih1,
                                const float* __restrict__ w_hh1,
                                __hip_bfloat16* __restrict__ o0,
                                __hip_bfloat16* __restrict__ o1,
                                __hip_bfloat16* __restrict__ o2)
{
    const int i = blockIdx.x * blockDim.x + threadIdx.x;  // 4096 x 256 = 1048576
    o0[i] = __float2bfloat16(w_hh0[i]);
    o1[i] = __float2bfloat16(w_ih1[i]);
    o2[i] = __float2bfloat16(w_hh1[i]);
}

__global__ void finalize_kernel(const float* __restrict__ x_stat,
                                const float* __restrict__ fc1_b,
                                const float* __restrict__ fc2_w, const float* __restrict__ fc2_b,
                                const float* __restrict__ fc3_w, const float* __restrict__ fc3_b,
                                const float* __restrict__ partial, float* __restrict__ out)
{
    const int b = threadIdx.x;  // 256
    float t0 = fc1_b[0], t1 = fc1_b[1];
    for (int jg = 0; jg < 16; jg++) {
        t0 += partial[((size_t)jg * Bc + b) * 2 + 0];
        t1 += partial[((size_t)jg * Bc + b) * 2 + 1];
    }
    const float s0 = fc2_b[0] + x_stat[b * 3 + 0] * fc2_w[0] + x_stat[b * 3 + 1] * fc2_w[1] + x_stat[b * 3 + 2] * fc2_w[2];
    const float s1 = fc2_b[1] + x_stat[b * 3 + 0] * fc2_w[3] + x_stat[b * 3 + 1] * fc2_w[4] + x_stat[b * 3 + 2] * fc2_w[5];
    out[b * 2 + 0] = fc3_b[0] + fc3_w[0] * s0 + fc3_w[1] * s1 + fc3_w[2] * t0 + fc3_w[3] * t1;
    out[b * 2 + 1] = fc3_b[1] + fc3_w[4] * s0 + fc3_w[5] * s1 + fc3_w[6] * t0 + fc3_w[7] * t1;
}

extern "C" void kernel_launch(void* const* d_in, const int* in_sizes, int n_in,
                              void* d_out, int out_size, void* d_ws, size_t ws_size,
                              hipStream_t stream)
{
    const float* x_time = (const float*)d_in[0];
    const float* x_stat = (const float*)d_in[1];
    const float* w_ih0 = (const float*)d_in[2];
    const float* w_hh0 = (const float*)d_in[3];
    const float* b0    = (const float*)d_in[4];
    const float* w_ih1 = (const float*)d_in[5];
    const float* w_hh1 = (const float*)d_in[6];
    const float* b1    = (const float*)d_in[7];
    const float* fc1_w = (const float*)d_in[8];
    const float* fc1_b = (const float*)d_in[9];
    const float* fc2_w = (const float*)d_in[10];
    const float* fc2_b = (const float*)d_in[11];
    const float* fc3_w = (const float*)d_in[12];
    const float* fc3_b = (const float*)d_in[13];

    char* base = (char*)d_ws;
    const size_t WSZ = (size_t)4 * Hc * Hc;              // 1048576 elements per weight matrix
    __hip_bfloat16* wbf_hh0 = (__hip_bfloat16*)base;               // 2MB
    __hip_bfloat16* wbf_ih1 = wbf_hh0 + WSZ;                       // 2MB
    __hip_bfloat16* wbf_hh1 = wbf_ih1 + WSZ;                       // 2MB
    __hip_bfloat16* h0 = wbf_hh1 + WSZ;                            // 2 x 256KB (bf16)
    __hip_bfloat16* h1 = h0 + (size_t)2 * Bc * Hc;                 // 2 x 256KB
    float* c0 = (float*)(h1 + (size_t)2 * Bc * Hc);                // 512KB
    float* c1 = c0 + (size_t)Bc * Hc;                              // 512KB
    float* partial = c1 + (size_t)Bc * Hc;                         // 32KB

    // zero: h0, h1 (bf16, 1MB), c0, c1 (1MB), partial (32KB)
    const size_t zoff = (size_t)3 * WSZ * sizeof(__hip_bfloat16);
    const size_t zlen = (size_t)4 * Bc * Hc * sizeof(__hip_bfloat16)
                      + (size_t)2 * Bc * Hc * sizeof(float)
                      + (size_t)16 * Bc * 2 * sizeof(float);
    hipMemsetAsync(base + zoff, 0, zlen, stream);

    convert_weights<<<4096, 256, 0, stream>>>(w_hh0, w_ih1, w_hh1, wbf_hh0, wbf_ih1, wbf_hh1);

    for (int i = 0; i <= Tc; i++) {
        const int p = i & 1;
        const __hip_bfloat16* h0r = h0 + (size_t)p * Bc * Hc;
        __hip_bfloat16* h0wp      = h0 + (size_t)(p ^ 1) * Bc * Hc;
        const __hip_bfloat16* h1r = h1 + (size_t)(p ^ 1) * Bc * Hc;
        __hip_bfloat16* h1wp      = h1 + (size_t)p * Bc * Hc;
        lstm_step_mfma<<<256, 256, 0, stream>>>(
            x_time, w_ih0, b0, b1, fc1_w,
            wbf_hh0, wbf_ih1, wbf_hh1,
            h0r, h0wp, c0, h1r, h1wp, c1, partial,
            i, i - 1, (i < Tc) ? 1 : 0, (i >= 1) ? 1 : 0);
    }
    finalize_kernel<<<1, 256, 0, stream>>>(x_stat, fc1_b, fc2_w, fc2_b, fc3_w, fc3_b,
                                           partial, (float*)d_out);
}